// Round 1
// baseline (327.452 us; speedup 1.0000x reference)
//
#include <hip/hip_runtime.h>
#include <hip/hip_bf16.h>
#include <cstdint>
#include <cstddef>

// IR-Net binary conv 3x3 s1 p1 + BN(inference) + hardtanh, B=32 Cin=Cout=256 H=W=56.
// Strategy: sign(x), sign(std(W)) are ternary -> exact bf16 MFMA implicit GEMM.
// out = clip(acc * S[co] + T[co]),  S = sw * gamma/sqrt(rv+eps), T = beta - rm*inv.

typedef short short8 __attribute__((ext_vector_type(8)));
typedef float floatx4 __attribute__((ext_vector_type(4)));

#define CIN   256
#define COUT  256
#define SPAT  3136   // 56*56
#define SPAD  3364   // 58*58 padded spatial
#define BATCH 32
#define NPIX  (BATCH*SPAT)  // 100352

// ---------------- weight prep ----------------
__device__ inline float block_reduce(float v, float* red, int t) {
  red[t] = v; __syncthreads();
#pragma unroll
  for (int o = 128; o > 0; o >>= 1) {
    if (t < o) red[t] += red[t + o];
    __syncthreads();
  }
  float r = red[0];
  __syncthreads();
  return r;
}

__global__ __launch_bounds__(256) void prep_w_kernel(
    const float* __restrict__ wgt, const float* __restrict__ gamma,
    const float* __restrict__ beta, const float* __restrict__ rmean,
    const float* __restrict__ rvar, uint16_t* __restrict__ wtap,
    float* __restrict__ Sc, float* __restrict__ Tc) {
  const int co = blockIdx.x;
  const int t  = threadIdx.x;
  __shared__ float red[256];
  const float* wc = wgt + (size_t)co * 2304;
  float v[9];
#pragma unroll
  for (int j = 0; j < 9; ++j) v[j] = wc[t + j * 256];
  float s = 0.f;
#pragma unroll
  for (int j = 0; j < 9; ++j) s += v[j];
  const float total = block_reduce(s, red, t);
  const float mean = total * (1.0f / 2304.0f);
  float ss = 0.f, sa = 0.f;
#pragma unroll
  for (int j = 0; j < 9; ++j) {
    float d = v[j] - mean;
    ss += d * d;
    sa += fabsf(d);
  }
  const float var_sum = block_reduce(ss, red, t);
  const float abs_sum = block_reduce(sa, red, t);
  const float stdv = sqrtf(var_sum / 2303.0f);       // unbiased (ddof=1)
  const float mean_abs = abs_sum / (2304.0f * stdv); // mean |bw|
  const float sw = exp2f(rintf(log2f(mean_abs)));    // rintf: half-even like jnp.round
#pragma unroll
  for (int j = 0; j < 9; ++j) {
    int i = t + j * 256;          // i = cin*9 + tap  (OIHW flat)
    int cin = i / 9;
    int tap = i - cin * 9;
    float d = v[j] - mean;
    uint16_t bits = (d > 0.f) ? 0x3F80u : ((d < 0.f) ? 0xBF80u : 0u); // bf16 +-1 / 0
    wtap[((size_t)tap * COUT + co) * CIN + cin] = bits;
  }
  if (t == 0) {
    float inv = gamma[co] / sqrtf(rvar[co] + 1e-5f);
    Sc[co] = sw * inv;
    Tc[co] = beta[co] - rmean[co] * inv;
  }
}

// ---------------- activation pack: sign(x) -> bf16, padded [b][58*58][cin] ----------------
__global__ __launch_bounds__(256) void pack_x_kernel(const float* __restrict__ x,
                                                     uint16_t* __restrict__ xp) {
  const int b   = blockIdx.y;
  const int s0  = blockIdx.x * 64;
  const int tid = threadIdx.x;
  __shared__ uint16_t xt[64][272];   // 64 spatial x 256 cin (+16 pad: b128-aligned rows)
  const int g  = tid >> 6;   // cin quarter 0..3
  const int si = tid & 63;   // spatial within chunk
  const float* xb = x + ((size_t)b * CIN + g * 64) * SPAT + s0 + si;
#pragma unroll 4
  for (int c2 = 0; c2 < 32; ++c2) {  // pair of channels per iter -> 4B LDS writes
    float v0 = xb[(size_t)(2 * c2) * SPAT];
    float v1 = xb[(size_t)(2 * c2 + 1) * SPAT];
    uint32_t b0 = (v0 > 0.f) ? 0x3F80u : ((v0 < 0.f) ? 0xBF80u : 0u);
    uint32_t b1 = (v1 > 0.f) ? 0x3F80u : ((v1 < 0.f) ? 0xBF80u : 0u);
    *(uint32_t*)&xt[si][g * 64 + 2 * c2] = b0 | (b1 << 16);
  }
  __syncthreads();
  const int row = tid >> 2;   // 0..63
  const int sub = tid & 3;    // cin quarter
  const int s = s0 + row;
  const int h = s / 56, w = s - h * 56;
  uint16_t* dst = xp + ((size_t)b * SPAD + (size_t)(h + 1) * 58 + (w + 1)) * CIN + sub * 64;
#pragma unroll
  for (int j = 0; j < 8; ++j)
    *(short8*)(dst + j * 8) = *(const short8*)&xt[row][sub * 64 + j * 8];
}

// ---------------- binary conv as implicit GEMM (bf16 MFMA) ----------------
// D[row=co][col=pixel]; A = Wtap[co][cin], B = Xp[cin][pixel] via padded gather.
__global__ __launch_bounds__(256) void conv_kernel(
    const uint16_t* __restrict__ xp, const uint16_t* __restrict__ wtap,
    const float* __restrict__ Sc, const float* __restrict__ Tc,
    float* __restrict__ out) {
  const int p0  = blockIdx.x * 128;
  const int co0 = blockIdx.y * 64;
  const int tid  = threadIdx.x;
  const int lane = tid & 63;
  const int wave = tid >> 6;
  const int wco = (wave >> 1) * 32;   // wave tile: 32 co x 64 p
  const int wp  = (wave & 1) * 64;

  __shared__ uint16_t Ws[64 * 72];    // [co][cin64] rows padded to 72
  __shared__ uint16_t Xs[128 * 72];   // [p][cin64]

  floatx4 acc[2][4];
#pragma unroll
  for (int m = 0; m < 2; ++m)
#pragma unroll
    for (int n = 0; n < 4; ++n) acc[m][n] = (floatx4){0.f, 0.f, 0.f, 0.f};

  // staging mapping
  const int xs_p    = tid >> 1;  // 0..127
  const int xs_half = tid & 1;   // 32-cin half
  const int ws_co   = tid >> 2;  // 0..63
  const int ws_q    = tid & 3;   // 16-cin quarter

  const int pg = p0 + xs_p;
  const int bb = pg / SPAT;
  const int sg = pg - bb * SPAT;
  const int hg = sg / 56;
  const int wg = sg - hg * 56;
  const size_t xbase = ((size_t)bb * SPAD + (size_t)(hg + 1) * 58 + (wg + 1)) * CIN
                       + (size_t)xs_half * 32;

  const int l15 = lane & 15;
  const int lk  = (lane >> 4) * 8;

  for (int tap = 0; tap < 9; ++tap) {
    const int dh = tap / 3 - 1, dw = tap - (tap / 3) * 3 - 1;
    const uint16_t* xsrc0 = xp + xbase + (ptrdiff_t)(dh * 58 + dw) * CIN;
    const uint16_t* wsrc0 = wtap + ((size_t)tap * COUT + co0 + ws_co) * CIN + ws_q * 16;
#pragma unroll 1
    for (int c0 = 0; c0 < CIN; c0 += 64) {
      __syncthreads();
      {  // stage Xs: 64B per thread, no masking (padding holds zeros)
        const short8* src = (const short8*)(xsrc0 + c0);
        short8 r0 = src[0], r1 = src[1], r2 = src[2], r3 = src[3];
        short8* d = (short8*)&Xs[xs_p * 72 + xs_half * 32];
        d[0] = r0; d[1] = r1; d[2] = r2; d[3] = r3;
      }
      {  // stage Ws: 32B per thread
        const short8* src = (const short8*)(wsrc0 + c0);
        short8 r0 = src[0], r1 = src[1];
        short8* d = (short8*)&Ws[ws_co * 72 + ws_q * 16];
        d[0] = r0; d[1] = r1;
      }
      __syncthreads();
#pragma unroll
      for (int kk = 0; kk < 64; kk += 32) {
        short8 af[2], bf[4];
#pragma unroll
        for (int m = 0; m < 2; ++m)
          af[m] = *(const short8*)&Ws[(wco + m * 16 + l15) * 72 + kk + lk];
#pragma unroll
        for (int n = 0; n < 4; ++n)
          bf[n] = *(const short8*)&Xs[(wp + n * 16 + l15) * 72 + kk + lk];
#pragma unroll
        for (int m = 0; m < 2; ++m)
#pragma unroll
          for (int n = 0; n < 4; ++n)
            acc[m][n] = __builtin_amdgcn_mfma_f32_16x16x32_bf16(af[m], bf[n], acc[m][n], 0, 0, 0);
      }
    }
  }

  // epilogue: out = clip(acc*S + T), out layout [b][co][s]
#pragma unroll
  for (int m = 0; m < 2; ++m) {
    const int cor0 = co0 + wco + m * 16 + (lane >> 4) * 4;  // global co of reg r=0
    float Sv[4], Tv[4];
#pragma unroll
    for (int r = 0; r < 4; ++r) { Sv[r] = Sc[cor0 + r]; Tv[r] = Tc[cor0 + r]; }
#pragma unroll
    for (int n = 0; n < 4; ++n) {
      const int p = p0 + wp + n * 16 + l15;
      const int b = p / SPAT;
      const int s = p - b * SPAT;
      float* op = out + ((size_t)b * COUT + cor0) * SPAT + s;
#pragma unroll
      for (int r = 0; r < 4; ++r) {
        float v = acc[m][n][r] * Sv[r] + Tv[r];
        v = fminf(1.0f, fmaxf(-1.0f, v));
        op[(size_t)r * SPAT] = v;
      }
    }
  }
}

extern "C" void kernel_launch(void* const* d_in, const int* in_sizes, int n_in,
                              void* d_out, int out_size, void* d_ws, size_t ws_size,
                              hipStream_t stream) {
  const float* x     = (const float*)d_in[0];
  const float* wgt   = (const float*)d_in[1];
  const float* gamma = (const float*)d_in[2];
  const float* beta  = (const float*)d_in[3];
  const float* rmean = (const float*)d_in[4];
  const float* rvar  = (const float*)d_in[5];
  float* out = (float*)d_out;

  // workspace layout
  uint16_t* xp = (uint16_t*)d_ws;
  const size_t xp_elems = (size_t)BATCH * SPAD * CIN;        // 27,557,888 (55.1 MB)
  uint16_t* wtap = xp + xp_elems;
  const size_t wtap_elems = (size_t)9 * COUT * CIN;          // 589,824 (1.2 MB)
  float* Sc = (float*)(wtap + wtap_elems);
  float* Tc = Sc + COUT;

  hipMemsetAsync(xp, 0, xp_elems * sizeof(uint16_t), stream);  // zero halo
  pack_x_kernel<<<dim3(49, BATCH), 256, 0, stream>>>(x, xp);
  prep_w_kernel<<<COUT, 256, 0, stream>>>(wgt, gamma, beta, rmean, rvar, wtap, Sc, Tc);
  conv_kernel<<<dim3(NPIX / 128, COUT / 64), 256, 0, stream>>>(xp, wtap, Sc, Tc, out);
}

// Round 2
// 207.821 us; speedup vs baseline: 1.5756x; 1.5756x over previous
//
#include <hip/hip_runtime.h>
#include <hip/hip_bf16.h>
#include <cstdint>
#include <cstddef>

// IR-Net binary conv 3x3 s1 p1 + BN(inference) + hardtanh, B=32 Cin=Cout=256 H=W=56.
// sign(x), sign(std(W)) ternary -> exact bf16 MFMA implicit GEMM.
// R2: LDS halo-span staging (9-tap reuse), co-tile 128, XOR-swizzled LDS,
//     global_load_lds X staging (pre-swizzled source), W reg-prefetch pipeline.

typedef short short8 __attribute__((ext_vector_type(8)));
typedef float floatx4 __attribute__((ext_vector_type(4)));

#define CIN   256
#define COUT  256
#define SPAT  3136   // 56*56
#define SPAD  3364   // 58*58 padded spatial
#define BATCH 32
#define SPAN  256    // padded-index span staged per tile (128 px + 2*59 halo + row jumps)

// ---------------- weight prep ----------------
__device__ inline float block_reduce(float v, float* red, int t) {
  red[t] = v; __syncthreads();
#pragma unroll
  for (int o = 128; o > 0; o >>= 1) {
    if (t < o) red[t] += red[t + o];
    __syncthreads();
  }
  float r = red[0];
  __syncthreads();
  return r;
}

__global__ __launch_bounds__(256) void prep_w_kernel(
    const float* __restrict__ wgt, const float* __restrict__ gamma,
    const float* __restrict__ beta, const float* __restrict__ rmean,
    const float* __restrict__ rvar, uint16_t* __restrict__ wtap,
    float* __restrict__ Sc, float* __restrict__ Tc) {
  const int co = blockIdx.x;
  const int t  = threadIdx.x;
  __shared__ float red[256];
  const float* wc = wgt + (size_t)co * 2304;
  float v[9];
#pragma unroll
  for (int j = 0; j < 9; ++j) v[j] = wc[t + j * 256];
  float s = 0.f;
#pragma unroll
  for (int j = 0; j < 9; ++j) s += v[j];
  const float total = block_reduce(s, red, t);
  const float mean = total * (1.0f / 2304.0f);
  float ss = 0.f, sa = 0.f;
#pragma unroll
  for (int j = 0; j < 9; ++j) {
    float d = v[j] - mean;
    ss += d * d;
    sa += fabsf(d);
  }
  const float var_sum = block_reduce(ss, red, t);
  const float abs_sum = block_reduce(sa, red, t);
  const float stdv = sqrtf(var_sum / 2303.0f);       // unbiased (ddof=1)
  const float mean_abs = abs_sum / (2304.0f * stdv); // mean |bw|
  const float sw = exp2f(rintf(log2f(mean_abs)));    // half-even like jnp.round
#pragma unroll
  for (int j = 0; j < 9; ++j) {
    int i = t + j * 256;          // i = cin*9 + tap  (OIHW flat)
    int cin = i / 9;
    int tap = i - cin * 9;
    float d = v[j] - mean;
    uint16_t bits = (d > 0.f) ? 0x3F80u : ((d < 0.f) ? 0xBF80u : 0u); // bf16 +-1 / 0
    wtap[((size_t)tap * COUT + co) * CIN + cin] = bits;
  }
  if (t == 0) {
    float inv = gamma[co] / sqrtf(rvar[co] + 1e-5f);
    Sc[co] = sw * inv;
    Tc[co] = beta[co] - rmean[co] * inv;
  }
}

// ---------------- activation pack: sign(x) -> bf16, padded [b][58*58][cin] ----------------
__global__ __launch_bounds__(256) void pack_x_kernel(const float* __restrict__ x,
                                                     uint16_t* __restrict__ xp) {
  const int b   = blockIdx.y;
  const int s0  = blockIdx.x * 64;
  const int tid = threadIdx.x;
  __shared__ uint16_t xt[64][272];
  const int g  = tid >> 6;
  const int si = tid & 63;
  const float* xb = x + ((size_t)b * CIN + g * 64) * SPAT + s0 + si;
#pragma unroll 4
  for (int c2 = 0; c2 < 32; ++c2) {
    float v0 = xb[(size_t)(2 * c2) * SPAT];
    float v1 = xb[(size_t)(2 * c2 + 1) * SPAT];
    uint32_t b0 = (v0 > 0.f) ? 0x3F80u : ((v0 < 0.f) ? 0xBF80u : 0u);
    uint32_t b1 = (v1 > 0.f) ? 0x3F80u : ((v1 < 0.f) ? 0xBF80u : 0u);
    *(uint32_t*)&xt[si][g * 64 + 2 * c2] = b0 | (b1 << 16);
  }
  __syncthreads();
  const int row = tid >> 2;
  const int sub = tid & 3;
  const int s = s0 + row;
  const int h = s / 56, w = s - h * 56;
  uint16_t* dst = xp + ((size_t)b * SPAD + (size_t)(h + 1) * 58 + (w + 1)) * CIN + sub * 64;
#pragma unroll
  for (int j = 0; j < 8; ++j)
    *(short8*)(dst + j * 8) = *(const short8*)&xt[row][sub * 64 + j * 8];
}

// ---------------- async global->LDS, 16B ----------------
__device__ __forceinline__ void gload_lds16(const void* g, void* l) {
  __builtin_amdgcn_global_load_lds(
      (const __attribute__((address_space(1))) uint32_t*)g,
      (__attribute__((address_space(3))) uint32_t*)l, 16, 0, 0);
}

// ---------------- binary conv as implicit GEMM (bf16 MFMA) ----------------
// Block: 128 co x 128 px, one image. X staged as padded-span [SPAN][64cin] with
// XOR-swizzled 16B chunks, reused across 9 taps. W reg-prefetched per tap.
__global__ __launch_bounds__(256, 2) void conv_kernel(
    const uint16_t* __restrict__ xp, const uint16_t* __restrict__ wtap,
    const float* __restrict__ Sc, const float* __restrict__ Tc,
    float* __restrict__ out) {
  const int tile = blockIdx.x;           // 0..24
  const int b    = blockIdx.y;           // 0..31
  const int co0  = blockIdx.z * 128;     // 0 or 128
  const int s0   = tile * 128;

  const int tid  = threadIdx.x;
  const int lane = tid & 63;
  const int wave = tid >> 6;
  const int wco  = (wave >> 1) * 64;     // wave tile: 64 co x 64 px
  const int wp   = (wave & 1) * 64;
  const int l15  = lane & 15;
  const int lk8  = (lane >> 4) * 8;

  __shared__ uint16_t Xs[2][SPAN * 64];  // 64 KB total
  __shared__ uint16_t Ws[128 * 64];      // 16 KB

  // padded-index base for this tile's span
  const int h0   = s0 / 56;
  const int base = (h0 + 1) * 58 + (s0 - h0 * 56 + 1) - 59;

  // per-lane B-frag pixel padded offsets (n=0..3); dummy px (s>=SPAT) still in-span
  int offn[4];
#pragma unroll
  for (int n = 0; n < 4; ++n) {
    int s = s0 + wp + n * 16 + l15;
    int h = s / 56;
    int w = s - h * 56;
    offn[n] = (h + 1) * 58 + (w + 1) - base;
  }
  // A-frag rows (loop-invariant)
  int arow[4], aswz[4];
#pragma unroll
  for (int m = 0; m < 4; ++m) {
    int r = wco + m * 16 + l15;
    arow[m] = r * 64;
    aswz[m] = r & 7;
  }

  const uint16_t* xb = xp + (size_t)b * SPAD * 256;

  // ---- X staging: 8 x 16B chunks per thread, linear LDS dest + inverse-swizzled source
  auto issueX = [&](int buf, int c0e) {
#pragma unroll
    for (int j = 0; j < 8; ++j) {
      int q   = j * 256 + tid;       // LDS 16B-chunk index
      int row = q >> 3;
      int c   = q & 7;
      int gr  = base + row;
      if (gr > SPAD - 1) gr = SPAD - 1;       // clamp (only feeds dummy px)
      int cp  = c ^ (row & 7);                 // source pre-swizzle
      gload_lds16(xb + (size_t)gr * 256 + c0e + cp * 8, &Xs[buf][q * 8]);
    }
  };

  // ---- W staging: reg-prefetch, swizzled ds_write
  const int wrow = tid >> 1;          // co row within tile
  const int wc0  = (tid & 1) * 4;     // first of 4 chunks
  const int wswz = wrow & 7;
  short8 wreg[4];
  auto loadW = [&](int idx) {         // idx = c0i*9 + tap
    int c0e = (idx / 9) * 64;
    int tap = idx - (idx / 9) * 9;
    const uint16_t* src = wtap + ((size_t)tap * COUT + co0 + wrow) * CIN + c0e + wc0 * 8;
#pragma unroll
    for (int i = 0; i < 4; ++i) wreg[i] = *(const short8*)(src + i * 8);
  };
  auto writeW = [&]() {
#pragma unroll
    for (int i = 0; i < 4; ++i)
      *(short8*)&Ws[wrow * 64 + (((wc0 + i) ^ wswz) << 3)] = wreg[i];
  };

  floatx4 acc[4][4];
#pragma unroll
  for (int m = 0; m < 4; ++m)
#pragma unroll
    for (int n = 0; n < 4; ++n) acc[m][n] = (floatx4){0.f, 0.f, 0.f, 0.f};

  // prologue: Xs[0] <- c0=0 (async), W(0) -> regs
  issueX(0, 0);
  loadW(0);
  __syncthreads();                 // vmcnt(0) drain: Xs[0] ready
  writeW();
  loadW(1);
  issueX(1, 64);                   // next cin-block, in flight across 9 taps
  __syncthreads();                 // Ws(idx 0) ready

  for (int idx = 0; idx < 36; ++idx) {
    const int c0i = idx / 9;
    const int tap = idx - c0i * 9;
    const int buf = c0i & 1;
    const int tapoff = (tap / 3 - 1) * 58 + (tap - (tap / 3) * 3 - 1);

    if (tap == 0 && c0i >= 1 && c0i < 3)
      issueX(buf ^ 1, (c0i + 1) * 64);   // buf^1 readers finished last c0-block

    int xrow[4], xswz[4];
#pragma unroll
    for (int n = 0; n < 4; ++n) {
      int r = offn[n] + tapoff;
      xrow[n] = r * 64;
      xswz[n] = r & 7;
    }
#pragma unroll
    for (int kk = 0; kk < 2; ++kk) {
      const int cbase = kk * 4 + (lk8 >> 3);   // chunk index {0,1,4,5}
      short8 af[4], bf[4];
#pragma unroll
      for (int m = 0; m < 4; ++m)
        af[m] = *(const short8*)&Ws[arow[m] + ((cbase ^ aswz[m]) << 3)];
#pragma unroll
      for (int n = 0; n < 4; ++n)
        bf[n] = *(const short8*)&Xs[buf][xrow[n] + ((cbase ^ xswz[n]) << 3)];
#pragma unroll
      for (int m = 0; m < 4; ++m)
#pragma unroll
        for (int n = 0; n < 4; ++n)
          acc[m][n] = __builtin_amdgcn_mfma_f32_16x16x32_bf16(af[m], bf[n], acc[m][n], 0, 0, 0);
    }
    __syncthreads();               // all waves done reading Ws(idx)
    if (idx + 1 < 36) {
      writeW();                    // wreg holds idx+1
      loadW(idx + 2 < 36 ? idx + 2 : 0);
    }
    __syncthreads();               // Ws(idx+1) ready
  }

  // epilogue: out = clip(acc*S + T), layout [b][co][s]
#pragma unroll
  for (int m = 0; m < 4; ++m) {
    const int cor0 = co0 + wco + m * 16 + (lane >> 4) * 4;
    float Sv[4], Tv[4];
#pragma unroll
    for (int r = 0; r < 4; ++r) { Sv[r] = Sc[cor0 + r]; Tv[r] = Tc[cor0 + r]; }
#pragma unroll
    for (int n = 0; n < 4; ++n) {
      const int s = s0 + wp + n * 16 + l15;
      if (s < SPAT) {
        float* op = out + ((size_t)b * COUT + cor0) * SPAT + s;
#pragma unroll
        for (int r = 0; r < 4; ++r) {
          float v = acc[m][n][r] * Sv[r] + Tv[r];
          v = fminf(1.0f, fmaxf(-1.0f, v));
          op[(size_t)r * SPAT] = v;
        }
      }
    }
  }
}

extern "C" void kernel_launch(void* const* d_in, const int* in_sizes, int n_in,
                              void* d_out, int out_size, void* d_ws, size_t ws_size,
                              hipStream_t stream) {
  const float* x     = (const float*)d_in[0];
  const float* wgt   = (const float*)d_in[1];
  const float* gamma = (const float*)d_in[2];
  const float* beta  = (const float*)d_in[3];
  const float* rmean = (const float*)d_in[4];
  const float* rvar  = (const float*)d_in[5];
  float* out = (float*)d_out;

  uint16_t* xp = (uint16_t*)d_ws;
  const size_t xp_elems = (size_t)BATCH * SPAD * CIN;        // 55.1 MB
  uint16_t* wtap = xp + xp_elems;
  const size_t wtap_elems = (size_t)9 * COUT * CIN;          // 1.2 MB
  float* Sc = (float*)(wtap + wtap_elems);
  float* Tc = Sc + COUT;

  hipMemsetAsync(xp, 0, xp_elems * sizeof(uint16_t), stream);  // zero halo
  pack_x_kernel<<<dim3(49, BATCH), 256, 0, stream>>>(x, xp);
  prep_w_kernel<<<COUT, 256, 0, stream>>>(wgt, gamma, beta, rmean, rvar, wtap, Sc, Tc);
  conv_kernel<<<dim3(25, BATCH, 2), 256, 0, stream>>>(xp, wtap, Sc, Tc, out);
}